// Round 1
// baseline (77.590 us; speedup 1.0000x reference)
//
#include <hip/hip_runtime.h>

// Problem constants (match reference)
#define NXG 2048
#define NYG 2048
// hx = hy = 1/2048 -> 1/h = 2048, 1/(2h) = 1024
__device__ __forceinline__ float inv_h()  { return 2048.0f; }
__device__ __forceinline__ float inv_2h() { return 1024.0f; }

#define BLOCK 256
#define GRID  1024

// Kernel 1: each thread processes float4 chunks of a row (4 consecutive y
// entries), computes vx^2+vy^2 for those 4 grid points, accumulates, then
// block-reduces into partial[blockIdx.x].
__global__ __launch_bounds__(BLOCK) void
energy_partial_kernel(const float* __restrict__ phi, float* __restrict__ partial) {
    const int totalChunks = (NXG * NYG) / 4;  // 1,048,576
    float acc = 0.0f;

    for (int c = blockIdx.x * blockDim.x + threadIdx.x;
         c < totalChunks;
         c += gridDim.x * blockDim.x) {
        const int i  = c >> 9;            // c / (NYG/4 = 512)
        const int j4 = (c & 511) << 2;    // starting y index of this chunk
        const float* row = phi + (size_t)i * NYG;

        const float4 self = *(const float4*)(row + j4);

        // x-direction: clamped neighbor rows + edge scale
        const int im1 = (i > 0)        ? i - 1 : 0;
        const int ip1 = (i < NXG - 1)  ? i + 1 : NXG - 1;
        const float sx = (i == 0 || i == NXG - 1) ? inv_h() : inv_2h();
        const float4 up = *(const float4*)(phi + (size_t)im1 * NYG + j4);
        const float4 dn = *(const float4*)(phi + (size_t)ip1 * NYG + j4);

        const float vx0 = (dn.x - up.x) * sx;
        const float vx1 = (dn.y - up.y) * sx;
        const float vx2 = (dn.z - up.z) * sx;
        const float vx3 = (dn.w - up.w) * sx;

        // y-direction within the row
        float vy0, vy1, vy2, vy3;
        if (j4 == 0) {
            vy0 = (self.y - self.x) * inv_h();      // forward diff at y=0
        } else {
            const float left = row[j4 - 1];
            vy0 = (self.y - left) * inv_2h();
        }
        vy1 = (self.z - self.x) * inv_2h();
        vy2 = (self.w - self.y) * inv_2h();
        if (j4 + 4 == NYG) {
            vy3 = (self.w - self.z) * inv_h();      // backward diff at y=ny-1
        } else {
            const float right = row[j4 + 4];
            vy3 = (right - self.z) * inv_2h();
        }

        acc += vx0 * vx0 + vx1 * vx1 + vx2 * vx2 + vx3 * vx3
             + vy0 * vy0 + vy1 * vy1 + vy2 * vy2 + vy3 * vy3;
    }

    // wave (64-lane) shuffle reduction
    #pragma unroll
    for (int off = 32; off > 0; off >>= 1)
        acc += __shfl_down(acc, off, 64);

    __shared__ float smem[BLOCK / 64];
    const int lane = threadIdx.x & 63;
    const int wave = threadIdx.x >> 6;
    if (lane == 0) smem[wave] = acc;
    __syncthreads();
    if (threadIdx.x == 0) {
        float s = 0.0f;
        #pragma unroll
        for (int w = 0; w < BLOCK / 64; ++w) s += smem[w];
        partial[blockIdx.x] = s;
    }
}

// Kernel 2: single block reduces GRID partials, writes 0.5 * sum.
__global__ __launch_bounds__(BLOCK) void
energy_finalize_kernel(const float* __restrict__ partial, float* __restrict__ out) {
    float acc = 0.0f;
    for (int idx = threadIdx.x; idx < GRID; idx += BLOCK)
        acc += partial[idx];

    #pragma unroll
    for (int off = 32; off > 0; off >>= 1)
        acc += __shfl_down(acc, off, 64);

    __shared__ float smem[BLOCK / 64];
    const int lane = threadIdx.x & 63;
    const int wave = threadIdx.x >> 6;
    if (lane == 0) smem[wave] = acc;
    __syncthreads();
    if (threadIdx.x == 0) {
        float s = 0.0f;
        #pragma unroll
        for (int w = 0; w < BLOCK / 64; ++w) s += smem[w];
        out[0] = 0.5f * s;
    }
}

extern "C" void kernel_launch(void* const* d_in, const int* in_sizes, int n_in,
                              void* d_out, int out_size, void* d_ws, size_t ws_size,
                              hipStream_t stream) {
    // d_in[0] = pos (unused by the reference), d_in[1] = potential_field [2048*2048] f32
    const float* phi = (const float*)d_in[1];
    float* out = (float*)d_out;
    float* partial = (float*)d_ws;  // GRID floats of scratch

    energy_partial_kernel<<<GRID, BLOCK, 0, stream>>>(phi, partial);
    energy_finalize_kernel<<<1, BLOCK, 0, stream>>>(partial, out);
}